// Round 9
// baseline (307.329 us; speedup 1.0000x reference)
//
#include <hip/hip_runtime.h>

#define HH 2048
#define WW 2048
#define NN (HH*WW)

static constexpr unsigned RANK0 = 1677721u;   // floor(0.4*(NN-1))
static constexpr unsigned KEYLO = 0xB000u;
static constexpr unsigned KEYHI_ = 0xC000u;
static constexpr int NBINS = 4096;
static constexpr int NPART = 2048;

// wavemorph: 1 wave per block, 64-col band (52 output cols), 16 output rows
static constexpr int WM_XT = 40;      // ceil(2048/52)
static constexpr int WM_YT = 128;     // 2048/16
static constexpr int WM_BLOCKS = WM_XT * WM_YT;

struct Scal {
  unsigned keyhiA, keyhiB, rA, rB;
  double thr, c0, c1;
};

// ws layout: [bufA NN floats][zeroed ctl: coarse|under|over|midA|midB|h2A|h2B][scal][part]
static constexpr size_t OFF_CTL    = (size_t)NN * 4;
static constexpr size_t OFF_COARSE = OFF_CTL;
static constexpr size_t OFF_UNDER  = OFF_COARSE + (size_t)NBINS * 4;
static constexpr size_t OFF_OVER   = OFF_UNDER + 4;
static constexpr size_t OFF_MIDA   = OFF_OVER + 4;
static constexpr size_t OFF_MIDB   = OFF_MIDA + 1024;
static constexpr size_t OFF_H2A    = OFF_MIDB + 1024;
static constexpr size_t OFF_H2B    = OFF_H2A + 65536ull * 4;
static constexpr size_t CTL_END    = OFF_H2B + 65536ull * 4;
static constexpr size_t CTL_BYTES  = CTL_END - OFF_CTL;
static constexpr size_t OFF_SCAL   = CTL_END;                // 8-aligned
static constexpr size_t OFF_PART   = OFF_SCAL + 64;

__device__ __forceinline__ float mx3(float a, float b, float c){ return fmaxf(fmaxf(a,b),c); }
__device__ __forceinline__ float mn3(float a, float b, float c){ return fminf(fminf(a,b),c); }

__device__ __forceinline__ unsigned keyf(float x){
  unsigned b = __float_as_uint(x);
  return (b & 0x80000000u) ? ~b : (b | 0x80000000u);
}
__device__ __forceinline__ float keyinv(unsigned k){
  unsigned b = (k & 0x80000000u) ? (k ^ 0x80000000u) : ~k;
  return __uint_as_float(b);
}

// push one produced row value into a 3-row rolling window
__device__ __forceinline__ void pushw(float Wv[3], float Wl[3], float Wr[3], float Wh[3],
                                      float v, bool domax){
  Wv[0]=Wv[1]; Wv[1]=Wv[2];
  Wl[0]=Wl[1]; Wl[1]=Wl[2];
  Wr[0]=Wr[1]; Wr[1]=Wr[2];
  Wh[0]=Wh[1]; Wh[1]=Wh[2];
  float vl = __shfl_up(v, 1);
  float vr = __shfl_down(v, 1);
  Wv[2]=v; Wl[2]=vl; Wr[2]=vr;
  Wh[2] = domax ? mx3(vl,v,vr) : mn3(vl,v,vr);
}

// compute one output value from window (p,c,n = rows 0,1,2)
__device__ __forceinline__ float firew(const float Wv[3], const float Wl[3],
                                       const float Wr[3], const float Wh[3], bool DIL){
  if (DIL){
    float Ah = Wh[1];
    float Av = mx3(Wv[0], Wv[1], Wv[2]);
    float Ad = mx3(Wl[0], Wv[1], Wr[2]);
    float Aa = mx3(Wr[0], Wv[1], Wl[2]);
    float M9 = mx3(Wh[0], Ah, Wh[2]);
    return fmaxf(M9, 1.0f + fminf(fminf(Ah,Av), fminf(Ad,Aa)));
  } else {
    float Bh = Wh[1];
    float Bv = mn3(Wv[0], Wv[1], Wv[2]);
    float Bd = mn3(Wl[0], Wv[1], Wr[2]);
    float Ba = mn3(Wr[0], Wv[1], Wl[2]);
    float m9 = mn3(Wh[0], Bh, Wh[2]);
    return fminf(m9, fmaxf(fmaxf(Bh,Bv), fmaxf(Bd,Ba)) - 1.0f);
  }
}

// All 6 smoothing ops (D,E,E,D,D,E) as a barrier-free 6-stage register pipeline.
// 1 wave per block, lane = column (64-col band, pristine lanes [6,57] = 52 output
// cols), walking 28 input rows. Shuffle garbage creeps 1 lane/stage from the wave
// edges and stays outside the output band; image zero-padding enforced per stage
// by per-lane col/row masks. Coarse histogram accumulated in LDS (no barriers:
// single wave is lockstep).
__global__ __launch_bounds__(64, 4)
void wavemorph_k(const float* __restrict__ in, float* __restrict__ out,
                 unsigned* __restrict__ gh, unsigned* __restrict__ under,
                 unsigned* __restrict__ over){
  __shared__ unsigned lh[NBINS/2];     // packed u16 bins; <=832 per bin per tile
  const int lane = threadIdx.x;
  for (int i = lane; i < NBINS/2; i += 64) lh[i] = 0;

  const int tx = blockIdx.x % WM_XT;
  const int ty = blockIdx.x / WM_XT;
  const int c0 = tx * 52, r0 = ty * 16;
  const int col = c0 - 6 + lane;
  const bool colbad = (unsigned)col >= (unsigned)WW;
  const bool dil[6] = {true,false,false,true,true,false};

  float Wv[6][3], Wl[6][3], Wr[6][3], Wh[6][3];
  #pragma unroll
  for (int s = 0; s < 6; s++)
    #pragma unroll
    for (int k = 0; k < 3; k++){ Wv[s][k]=0.f; Wl[s][k]=0.f; Wr[s][k]=0.f; Wh[s][k]=0.f; }

  unsigned uc = 0, oc = 0;

  #pragma unroll 1
  for (int j = 0; j < 28; j++){
    int gr = r0 - 6 + j;
    float v = 0.f;
    if (!colbad && (unsigned)gr < (unsigned)HH) v = in[(size_t)gr*WW + col];
    pushw(Wv[0], Wl[0], Wr[0], Wh[0], v, true);      // W[0] feeds stage 1 (D)

    #pragma unroll
    for (int s = 1; s <= 6; s++){
      if (j >= 2*s){
        float w = firew(Wv[s-1], Wl[s-1], Wr[s-1], Wh[s-1], dil[s-1]);
        int gro = r0 - 6 + (j - s);
        if (colbad || (unsigned)gro >= (unsigned)HH) w = 0.f;
        if (s < 6){
          pushw(Wv[s], Wl[s], Wr[s], Wh[s], w, dil[s]);   // hx type = next stage
        } else {
          // output row gro = r0 + j - 12 in [r0, r0+15]
          if (lane >= 6 && lane <= 57 && col < WW){
            out[(size_t)gro*WW + col] = w;
            unsigned key = keyf(w);
            unsigned hi = key >> 16;
            if (hi >= KEYLO && hi < KEYHI_){
              unsigned bin = hi - KEYLO;
              atomicAdd(&lh[bin >> 1], 1u << ((bin & 1) << 4));
            }
            else if (hi < KEYLO) uc++;
            else                 oc++;
          }
        }
      }
    }
  }

  // merge (single wave: LDS ops are in-order, no barrier needed)
  for (int i = lane; i < NBINS/2; i += 64){
    unsigned w = lh[i];
    if (w & 0xFFFFu) atomicAdd(&gh[2*i],   w & 0xFFFFu);
    if (w >> 16)     atomicAdd(&gh[2*i+1], w >> 16);
  }
  for (int off = 32; off; off >>= 1){
    uc += __shfl_down(uc, off);
    oc += __shfl_down(oc, off);
  }
  if (lane == 0){
    if (uc) atomicAdd(under, uc);
    if (oc) atomicAdd(over, oc);
  }
}

__global__ void scan_coarse_k(const unsigned* __restrict__ gh, const unsigned* __restrict__ under,
                              Scal* __restrict__ sc){
  __shared__ unsigned part[256];
  __shared__ unsigned excl[256];
  int t = threadIdx.x;
  unsigned loc = 0;
  #pragma unroll
  for (int i = 0; i < NBINS/256; i++) loc += gh[t*(NBINS/256) + i];
  part[t] = loc;
  __syncthreads();
  if (t == 0){
    unsigned run = under[0];
    for (int i = 0; i < 256; i++){ excl[i] = run; run += part[i]; }
  }
  __syncthreads();
  unsigned run = excl[t];
  const unsigned r0 = RANK0, r1 = RANK0 + 1;
  #pragma unroll
  for (int i = 0; i < NBINS/256; i++){
    unsigned idx = t*(NBINS/256) + i;
    unsigned cc = gh[idx];
    if (cc){
      if (r0 >= run && r0 - run < cc){ sc->keyhiA = KEYLO + idx; sc->rA = r0 - run; }
      if (r1 >= run && r1 - run < cc){ sc->keyhiB = KEYLO + idx; sc->rB = r1 - run; }
    }
    run += cc;
  }
}

// ONE fine pass: 256-bin mid hist (LDS) + speculative 65536-bin (mid,low) 2D hist
__global__ __launch_bounds__(256)
void fine2d_k(const float* __restrict__ x, const Scal* __restrict__ sc,
              unsigned* __restrict__ midA, unsigned* __restrict__ midB,
              unsigned* __restrict__ h2A, unsigned* __restrict__ h2B){
  __shared__ unsigned hA[256], hB[256];
  hA[threadIdx.x] = 0; hB[threadIdx.x] = 0;
  __syncthreads();
  unsigned ha = sc->keyhiA, hb = sc->keyhiB;
  bool dup = (ha == hb);
  const int nItems = NN/4;
  for (int it = blockIdx.x*blockDim.x + threadIdx.x; it < nItems; it += gridDim.x*blockDim.x){
    float4 v = reinterpret_cast<const float4*>(x)[it];
    float vv[4] = {v.x, v.y, v.z, v.w};
    #pragma unroll
    for (int j = 0; j < 4; j++){
      unsigned key = keyf(vv[j]);
      unsigned hi = key >> 16;
      if (hi == ha){ atomicAdd(&hA[(key>>8)&255], 1u); atomicAdd(&h2A[key & 0xFFFFu], 1u); }
      else if (hi == hb){ atomicAdd(&hB[(key>>8)&255], 1u); atomicAdd(&h2B[key & 0xFFFFu], 1u); }
    }
  }
  __syncthreads();
  if (hA[threadIdx.x]) atomicAdd(&midA[threadIdx.x], hA[threadIdx.x]);
  if (!dup && hB[threadIdx.x]) atomicAdd(&midB[threadIdx.x], hB[threadIdx.x]);
}

// resolve mid byte (from midA/midB) then low byte (from the matching h2 row) -> thr
__global__ void scan_ml_k(const unsigned* __restrict__ midA, const unsigned* __restrict__ midB,
                          const unsigned* __restrict__ h2A, const unsigned* __restrict__ h2B,
                          Scal* __restrict__ sc){
  __shared__ unsigned h[256], excl[256];
  __shared__ unsigned res[6];   // mA, rA2, mB, rB2, lowA, lowB
  int t = threadIdx.x;
  unsigned ha = sc->keyhiA, hb = sc->keyhiB;
  bool dupHi = (ha == hb);
  unsigned rA = sc->rA, rB = sc->rB;

  h[t] = midA[t];
  __syncthreads();
  if (t == 0){ unsigned run = 0; for (int i = 0; i < 256; i++){ excl[i] = run; run += h[i]; } }
  __syncthreads();
  if (rA >= excl[t] && rA - excl[t] < h[t]){ res[0] = (unsigned)t; res[1] = rA - excl[t]; }
  if (dupHi && rB >= excl[t] && rB - excl[t] < h[t]){ res[2] = (unsigned)t; res[3] = rB - excl[t]; }
  __syncthreads();
  if (!dupHi){
    h[t] = midB[t];
    __syncthreads();
    if (t == 0){ unsigned run = 0; for (int i = 0; i < 256; i++){ excl[i] = run; run += h[i]; } }
    __syncthreads();
    if (rB >= excl[t] && rB - excl[t] < h[t]){ res[2] = (unsigned)t; res[3] = rB - excl[t]; }
    __syncthreads();
  }
  unsigned mA = res[0], rA2 = res[1], mB = res[2], rB2 = res[3];
  bool dupMid = dupHi && (mA == mB);

  h[t] = h2A[mA*256 + t];
  __syncthreads();
  if (t == 0){ unsigned run = 0; for (int i = 0; i < 256; i++){ excl[i] = run; run += h[i]; } }
  __syncthreads();
  if (rA2 >= excl[t] && rA2 - excl[t] < h[t]) res[4] = (unsigned)t;
  if (dupMid && rB2 >= excl[t] && rB2 - excl[t] < h[t]) res[5] = (unsigned)t;
  __syncthreads();
  if (!dupMid){
    const unsigned* srcH = dupHi ? h2A : h2B;
    h[t] = srcH[mB*256 + t];
    __syncthreads();
    if (t == 0){ unsigned run = 0; for (int i = 0; i < 256; i++){ excl[i] = run; run += h[i]; } }
    __syncthreads();
    if (rB2 >= excl[t] && rB2 - excl[t] < h[t]) res[5] = (unsigned)t;
    __syncthreads();
  }
  if (t == 0){
    unsigned ka = (ha << 16) | (mA << 8) | res[4];
    unsigned kb = (hb << 16) | (mB << 8) | res[5];
    double va = (double)keyinv(ka), vb = (double)keyinv(kb);
    const double FRAC = 0.4*(double)(NN-1) - (double)RANK0;   // np's gamma
    sc->thr = va + (vb - va) * FRAC;
  }
}

// 6-col window of global row via 1 float4 + shuffles (scalar patch on lanes 0/63)
__device__ __forceinline__ void growin(const float* __restrict__ p, int row, int q, int lane,
                                       float w[6]){
  if ((unsigned)row >= (unsigned)HH){
    w[0]=w[1]=w[2]=w[3]=w[4]=w[5]=0.f;
    return;
  }
  const float* rp = p + (size_t)row * WW;
  float4 v = *reinterpret_cast<const float4*>(rp + 4*q);
  float L = __shfl_up(v.w, 1);
  float R = __shfl_down(v.x, 1);
  if (q == 0)            L = 0.f;
  else if (lane == 0)    L = rp[4*q - 1];
  if (q == 511)          R = 0.f;
  else if (lane == 63)   R = rp[4*q + 4];
  w[0]=L; w[1]=v.x; w[2]=v.y; w[3]=v.z; w[4]=v.w; w[5]=R;
}

// balloon result computed ON THE FLY (no store): f64 partial sums of origin, nx, origin*nx
__global__ __launch_bounds__(256)
void sums_k(const float* __restrict__ x, const float* __restrict__ orig,
            const Scal* __restrict__ sc, double* __restrict__ part){
  double thr = sc->thr;
  double s0 = 0.0, s1 = 0.0, s2 = 0.0;
  const int nItems = NN/4;
  const int lane = threadIdx.x & 63;
  for (int it = blockIdx.x*blockDim.x + threadIdx.x; it < nItems; it += gridDim.x*blockDim.x){
    int i = it >> 9;
    int q = it & 511;
    float a[6], b[6], c[6];
    growin(x, i-1, q, lane, a);
    growin(x, i,   q, lane, b);
    growin(x, i+1, q, lane, c);
    float4 og = *reinterpret_cast<const float4*>(orig + (size_t)i*WW + 4*q);
    float ov[4] = {og.x, og.y, og.z, og.w};
    #pragma unroll
    for (int j = 0; j < 4; j++){
      float M9 = mx3(mx3(a[j],a[j+1],a[j+2]), mx3(b[j],b[j+1],b[j+2]), mx3(c[j],c[j+1],c[j+2]));
      float nx = ((double)ov[j] > thr) ? (1.0f + M9) : b[j+1];
      s0 += (double)ov[j];
      s1 += (double)nx;
      s2 += (double)ov[j] * (double)nx;
    }
  }
  for (int off = 32; off > 0; off >>= 1){
    s0 += __shfl_down(s0, off);
    s1 += __shfl_down(s1, off);
    s2 += __shfl_down(s2, off);
  }
  __shared__ double red[4][3];
  int wv = threadIdx.x >> 6;
  if (lane == 0){ red[wv][0] = s0; red[wv][1] = s1; red[wv][2] = s2; }
  __syncthreads();
  if (threadIdx.x == 0){
    part[blockIdx.x*3+0] = red[0][0]+red[1][0]+red[2][0]+red[3][0];
    part[blockIdx.x*3+1] = red[0][1]+red[1][1]+red[2][1]+red[3][1];
    part[blockIdx.x*3+2] = red[0][2]+red[1][2]+red[2][2]+red[3][2];
  }
}

__global__ void c0c1_k(const double* __restrict__ part, Scal* __restrict__ sc){
  int t = threadIdx.x;
  double s0 = 0, s1 = 0, s2 = 0;
  for (int b = t; b < NPART; b += 256){
    s0 += part[b*3+0]; s1 += part[b*3+1]; s2 += part[b*3+2];
  }
  for (int off = 32; off > 0; off >>= 1){
    s0 += __shfl_down(s0, off);
    s1 += __shfl_down(s1, off);
    s2 += __shfl_down(s2, off);
  }
  __shared__ double red[4][3];
  int lane = t & 63, wv = t >> 6;
  if (lane == 0){ red[wv][0] = s0; red[wv][1] = s1; red[wv][2] = s2; }
  __syncthreads();
  if (t == 0){
    double So = red[0][0]+red[1][0]+red[2][0]+red[3][0];
    double Sx = red[0][1]+red[1][1]+red[2][1]+red[3][1];
    double Sox= red[0][2]+red[1][2]+red[2][2]+red[3][2];
    sc->c0 = (So - Sox) / ((double)NN - Sx + 1e-8);
    sc->c1 = Sox / (Sx + 1e-8);
  }
}

// rare fallback: recompute nx at one pixel (exact same FP ops as sums_k path)
__device__ __noinline__ float nx_at(const float* __restrict__ x, float o, double thr,
                                    int i, int c){
  if (!((double)o > thr)){
    return x[(size_t)i*WW + c];
  }
  float M9 = 0.f;
  bool first = true;
  #pragma unroll
  for (int dr = -1; dr <= 1; dr++){
    #pragma unroll
    for (int dc = -1; dc <= 1; dc++){
      int r = i + dr, cc = c + dc;
      float v = ((unsigned)r < (unsigned)HH && (unsigned)cc < (unsigned)WW)
                ? x[(size_t)r*WW + cc] : 0.f;
      M9 = first ? v : fmaxf(M9, v);
      first = false;
    }
  }
  return 1.0f + M9;
}

// final: pure elementwise Chan-Vese (cv from origin only); nx needed only when cv==0
__global__ __launch_bounds__(256)
void final_k(const float* __restrict__ x, const float* __restrict__ orig,
             const Scal* __restrict__ sc, float* __restrict__ out){
  double thr = sc->thr, c0 = sc->c0, c1 = sc->c1;
  const int nItems = NN/4;
  for (int it = blockIdx.x*blockDim.x + threadIdx.x; it < nItems; it += gridDim.x*blockDim.x){
    float4 og = reinterpret_cast<const float4*>(orig)[it];
    float ov[4] = {og.x, og.y, og.z, og.w};
    float r[4];
    #pragma unroll
    for (int j = 0; j < 4; j++){
      double o = (double)ov[j];
      double d1 = o - c1, d0 = o - c0;
      double cv = d1*d1 - d0*d0;
      if (cv < 0.0)      r[j] = 1.0f;
      else if (cv > 0.0) r[j] = 0.0f;
      else {
        int i = it >> 9, q = it & 511;
        r[j] = nx_at(x, ov[j], thr, i, 4*q + j);
      }
    }
    reinterpret_cast<float4*>(out)[it] = make_float4(r[0],r[1],r[2],r[3]);
  }
}

extern "C" void kernel_launch(void* const* d_in, const int* in_sizes, int n_in,
                              void* d_out, int out_size, void* d_ws, size_t ws_size,
                              hipStream_t stream) {
  const float* input  = (const float*)d_in[0];
  const float* origin = (const float*)d_in[1];
  float* out = (float*)d_out;

  char* ws = (char*)d_ws;
  float*    bufA   = (float*)ws;
  unsigned* coarse = (unsigned*)(ws + OFF_COARSE);
  unsigned* under  = (unsigned*)(ws + OFF_UNDER);
  unsigned* over   = (unsigned*)(ws + OFF_OVER);
  unsigned* midA   = (unsigned*)(ws + OFF_MIDA);
  unsigned* midB   = (unsigned*)(ws + OFF_MIDB);
  unsigned* h2A    = (unsigned*)(ws + OFF_H2A);
  unsigned* h2B    = (unsigned*)(ws + OFF_H2B);
  Scal*     scal   = (Scal*)(ws + OFF_SCAL);
  double*   part   = (double*)(ws + OFF_PART);

  hipMemsetAsync(ws + OFF_CTL, 0, CTL_BYTES, stream);

  // all 6 smoothing ops + coarse hist; x -> bufA (d_out written only by final_k)
  wavemorph_k<<<WM_BLOCKS, 64, 0, stream>>>(input, bufA, coarse, under, over);

  scan_coarse_k<<<1, 256, 0, stream>>>(coarse, under, scal);
  fine2d_k<<<2048, 256, 0, stream>>>(bufA, scal, midA, midB, h2A, h2B);
  scan_ml_k<<<1, 256, 0, stream>>>(midA, midB, h2A, h2B, scal);

  sums_k<<<NPART, 256, 0, stream>>>(bufA, origin, scal, part);
  c0c1_k<<<1, 256, 0, stream>>>(part, scal);
  final_k<<<2048, 256, 0, stream>>>(bufA, origin, scal, out);
}

// Round 10
// 127.437 us; speedup vs baseline: 2.4116x; 2.4116x over previous
//
#include <hip/hip_runtime.h>

#define HH 2048
#define WW 2048
#define NN (HH*WW)

static constexpr unsigned RANK0 = 1677721u;   // floor(0.4*(NN-1))
static constexpr unsigned KEYLO = 0xB000u;
static constexpr unsigned KEYHI_ = 0xC000u;
static constexpr int NBINS = 4096;
static constexpr int NPART = 512;

// fused morph tile geometry (round-3 proven): 32x128 tile, halo 6
#define TH 32
#define TW 128
#define LR 44            // TH + 12 rows (halo 6 each side)
#define LCP 148          // padded LDS row stride in floats (data cols [0,144))

struct Scal {
  unsigned keyhiA, keyhiB, rA, rB;
  double thr, c0, c1;
};

// ws layout: [bufA NN floats][zeroed ctl: coarse|under|over|midA|midB|h2A|h2B][scal][part]
static constexpr size_t OFF_CTL    = (size_t)NN * 4;
static constexpr size_t OFF_COARSE = OFF_CTL;
static constexpr size_t OFF_UNDER  = OFF_COARSE + (size_t)NBINS * 4;
static constexpr size_t OFF_OVER   = OFF_UNDER + 4;
static constexpr size_t OFF_MIDA   = OFF_OVER + 4;
static constexpr size_t OFF_MIDB   = OFF_MIDA + 1024;
static constexpr size_t OFF_H2A    = OFF_MIDB + 1024;
static constexpr size_t OFF_H2B    = OFF_H2A + 65536ull * 4;
static constexpr size_t CTL_END    = OFF_H2B + 65536ull * 4;
static constexpr size_t CTL_BYTES  = CTL_END - OFF_CTL;
static constexpr size_t OFF_SCAL   = CTL_END;                // 8-aligned
static constexpr size_t OFF_PART   = OFF_SCAL + 64;

__device__ __forceinline__ float mx3(float a, float b, float c){ return fmaxf(fmaxf(a,b),c); }
__device__ __forceinline__ float mn3(float a, float b, float c){ return fminf(fminf(a,b),c); }

__device__ __forceinline__ unsigned keyf(float x){
  unsigned b = __float_as_uint(x);
  return (b & 0x80000000u) ? ~b : (b | 0x80000000u);
}
__device__ __forceinline__ float keyinv(unsigned k){
  unsigned b = (k & 0x80000000u) ? (k ^ 0x80000000u) : ~k;
  return __uint_as_float(b);
}

// read one LDS row window for col-group g: aligned float4 + neighbors via shuffle;
// wave-boundary / tile-edge lanes patch with a clamped LDS read (clamp garbage
// only touches cols 0/143 which stay outside the pristine ring at every stage).
__device__ __forceinline__ void loadrow(const float* __restrict__ src, int lr, int g, int lane,
                                        float4& v, float& L, float& R){
  v = *reinterpret_cast<const float4*>(&src[lr*LCP + 4*g]);
  L = __shfl_up(v.w, 1);
  R = __shfl_down(v.x, 1);
  if (lane == 0 || g == 0)   L = src[lr*LCP + (g ? 4*g - 1 : 0)];
  if (lane == 63 || g == 35) R = src[lr*LCP + ((g == 35) ? 143 : 4*g + 4)];
}

__device__ __forceinline__ void morph4(bool DIL,
    const float pr[6], const float cr[6], const float nr[6], float w[4]){
  #pragma unroll
  for (int i = 0; i < 4; i++){
    if (DIL){
      float Ah = mx3(cr[i],   cr[i+1], cr[i+2]);
      float Av = mx3(pr[i+1], cr[i+1], nr[i+1]);
      float Ad = mx3(pr[i],   cr[i+1], nr[i+2]);
      float Aa = mx3(pr[i+2], cr[i+1], nr[i]);
      float tm = mx3(pr[i], pr[i+1], pr[i+2]);
      float bm = mx3(nr[i], nr[i+1], nr[i+2]);
      float M9 = mx3(tm, Ah, bm);
      w[i] = fmaxf(M9, 1.0f + fminf(fminf(Ah,Av), fminf(Ad,Aa)));
    } else {
      float Bh = mn3(cr[i],   cr[i+1], cr[i+2]);
      float Bv = mn3(pr[i+1], cr[i+1], nr[i+1]);
      float Bd = mn3(pr[i],   cr[i+1], nr[i+2]);
      float Ba = mn3(pr[i+2], cr[i+1], nr[i]);
      float tm = mn3(pr[i], pr[i+1], pr[i+2]);
      float bm = mn3(nr[i], nr[i+1], nr[i+2]);
      float m9 = mn3(tm, Bh, bm);
      w[i] = fminf(m9, fmaxf(fmaxf(Bh,Bv), fmaxf(Bd,Ba)) - 1.0f);
    }
  }
}

// All 6 smoothing ops (D,E,E,D,D,E) on a 32x128 tile, fully in LDS (round-3
// verbatim: 61.7us measured), plus the coarse histogram of the final values
// (hist storage aliases the idle buffer).
__global__ __launch_bounds__(256)
void fused_morph_k(const float* __restrict__ in, float* __restrict__ out,
                   unsigned* __restrict__ gh, unsigned* __restrict__ under,
                   unsigned* __restrict__ over){
  __shared__ float lds[2][LR*LCP];
  const int tilec = blockIdx.x & 15;       // 16 col tiles
  const int tiler = blockIdx.x >> 4;       // 64 row tiles
  const int r0 = tiler*TH, c0 = tilec*TW;

  // ---- load 44 rows x 36 aligned float4 (cols c0-8 .. c0+136), zero-padded ----
  for (int idx = threadIdx.x; idx < LR*36; idx += 256){
    int lr = idx / 36, g = idx % 36;
    int gr = r0 - 6 + lr, gc = c0 - 8 + 4*g;
    float4 v = make_float4(0.f,0.f,0.f,0.f);
    if ((unsigned)gr < (unsigned)HH && (unsigned)gc < (unsigned)WW)
      v = *reinterpret_cast<const float4*>(in + (size_t)gr*WW + gc);
    *reinterpret_cast<float4*>(&lds[0][lr*LCP + 4*g]) = v;
  }
  __syncthreads();

  const int t = threadIdx.x;
  const int g = t % 36, s = t / 36;        // strip s covers compute rows [6s+1, 6s+7)
  const bool active = (t < 252);
  const int lane = t & 63;
  const int gcBase = c0 - 8 + 4*g;
  const bool dilf[6] = {true,false,false,true,true,false};

  #pragma unroll 1
  for (int st = 0; st < 6; st++){
    const float* src = lds[st & 1];
    float*       dst = lds[(st & 1) ^ 1];
    if (active){
      const bool DIL = dilf[st];
      float4 vp, vc;  float pL,pR,cL,cR;
      loadrow(src, 6*s,     g, lane, vp, pL, pR);
      loadrow(src, 6*s + 1, g, lane, vc, cL, cR);
      #pragma unroll 1
      for (int k = 0; k < 6; k++){
        int lr = 6*s + 1 + k;
        float4 vn; float nL,nR;
        loadrow(src, lr + 1, g, lane, vn, nL, nR);
        float pr[6] = {pL, vp.x, vp.y, vp.z, vp.w, pR};
        float cr[6] = {cL, vc.x, vc.y, vc.z, vc.w, cR};
        float nr[6] = {nL, vn.x, vn.y, vn.z, vn.w, nR};
        float w[4];
        morph4(DIL, pr, cr, nr, w);
        int gr = r0 - 6 + lr;
        if ((unsigned)gr >= (unsigned)HH){
          w[0]=w[1]=w[2]=w[3]=0.f;
        } else {
          #pragma unroll
          for (int i = 0; i < 4; i++)
            if ((unsigned)(gcBase + i) >= (unsigned)WW) w[i] = 0.f;
        }
        *reinterpret_cast<float4*>(&dst[lr*LCP + 4*g]) = make_float4(w[0],w[1],w[2],w[3]);
        vp = vc; pL = cL; pR = cR;
        vc = vn; cL = nL; cR = nR;
      }
    }
    __syncthreads();
  }
  // final values live in lds[0]; lds[1] is free -> coarse histogram storage
  unsigned* lh = reinterpret_cast<unsigned*>(&lds[1][0]);
  for (int i = threadIdx.x; i < NBINS; i += 256) lh[i] = 0;
  __syncthreads();

  unsigned uc = 0, oc = 0;
  for (int idx = threadIdx.x; idx < TH*(TW/4); idx += 256){
    int row = idx >> 5, gg = idx & 31;
    float4 v = *reinterpret_cast<const float4*>(&lds[0][(row+6)*LCP + 8 + 4*gg]);
    *reinterpret_cast<float4*>(out + (size_t)(r0+row)*WW + c0 + 4*gg) = v;
    float vv[4] = {v.x, v.y, v.z, v.w};
    #pragma unroll
    for (int i = 0; i < 4; i++){
      unsigned key = keyf(vv[i]);
      unsigned hi = key >> 16;
      if (hi >= KEYLO && hi < KEYHI_) atomicAdd(&lh[hi - KEYLO], 1u);
      else if (hi < KEYLO)            uc++;
      else                            oc++;
    }
  }
  __syncthreads();
  for (int i = threadIdx.x; i < NBINS; i += 256){
    unsigned c = lh[i];
    if (c) atomicAdd(&gh[i], c);
  }
  if (uc) atomicAdd(under, uc);
  if (oc) atomicAdd(over, oc);
}

__global__ void scan_coarse_k(const unsigned* __restrict__ gh, const unsigned* __restrict__ under,
                              Scal* __restrict__ sc){
  __shared__ unsigned part[256];
  __shared__ unsigned excl[256];
  int t = threadIdx.x;
  unsigned loc = 0;
  #pragma unroll
  for (int i = 0; i < NBINS/256; i++) loc += gh[t*(NBINS/256) + i];
  part[t] = loc;
  __syncthreads();
  if (t == 0){
    unsigned run = under[0];
    for (int i = 0; i < 256; i++){ excl[i] = run; run += part[i]; }
  }
  __syncthreads();
  unsigned run = excl[t];
  const unsigned r0 = RANK0, r1 = RANK0 + 1;
  #pragma unroll
  for (int i = 0; i < NBINS/256; i++){
    unsigned idx = t*(NBINS/256) + i;
    unsigned cc = gh[idx];
    if (cc){
      if (r0 >= run && r0 - run < cc){ sc->keyhiA = KEYLO + idx; sc->rA = r0 - run; }
      if (r1 >= run && r1 - run < cc){ sc->keyhiB = KEYLO + idx; sc->rB = r1 - run; }
    }
    run += cc;
  }
}

// ONE fine pass: 256-bin mid hist (LDS) + speculative 65536-bin (mid,low) 2D hist
__global__ __launch_bounds__(256)
void fine2d_k(const float* __restrict__ x, const Scal* __restrict__ sc,
              unsigned* __restrict__ midA, unsigned* __restrict__ midB,
              unsigned* __restrict__ h2A, unsigned* __restrict__ h2B){
  __shared__ unsigned hA[256], hB[256];
  hA[threadIdx.x] = 0; hB[threadIdx.x] = 0;
  __syncthreads();
  unsigned ha = sc->keyhiA, hb = sc->keyhiB;
  bool dup = (ha == hb);
  const int nItems = NN/4;
  for (int it = blockIdx.x*blockDim.x + threadIdx.x; it < nItems; it += gridDim.x*blockDim.x){
    float4 v = reinterpret_cast<const float4*>(x)[it];
    float vv[4] = {v.x, v.y, v.z, v.w};
    #pragma unroll
    for (int j = 0; j < 4; j++){
      unsigned key = keyf(vv[j]);
      unsigned hi = key >> 16;
      if (hi == ha){ atomicAdd(&hA[(key>>8)&255], 1u); atomicAdd(&h2A[key & 0xFFFFu], 1u); }
      else if (hi == hb){ atomicAdd(&hB[(key>>8)&255], 1u); atomicAdd(&h2B[key & 0xFFFFu], 1u); }
    }
  }
  __syncthreads();
  if (hA[threadIdx.x]) atomicAdd(&midA[threadIdx.x], hA[threadIdx.x]);
  if (!dup && hB[threadIdx.x]) atomicAdd(&midB[threadIdx.x], hB[threadIdx.x]);
}

// resolve mid byte (from midA/midB) then low byte (from the matching h2 row) -> thr
__global__ void scan_ml_k(const unsigned* __restrict__ midA, const unsigned* __restrict__ midB,
                          const unsigned* __restrict__ h2A, const unsigned* __restrict__ h2B,
                          Scal* __restrict__ sc){
  __shared__ unsigned h[256], excl[256];
  __shared__ unsigned res[6];   // mA, rA2, mB, rB2, lowA, lowB
  int t = threadIdx.x;
  unsigned ha = sc->keyhiA, hb = sc->keyhiB;
  bool dupHi = (ha == hb);
  unsigned rA = sc->rA, rB = sc->rB;

  h[t] = midA[t];
  __syncthreads();
  if (t == 0){ unsigned run = 0; for (int i = 0; i < 256; i++){ excl[i] = run; run += h[i]; } }
  __syncthreads();
  if (rA >= excl[t] && rA - excl[t] < h[t]){ res[0] = (unsigned)t; res[1] = rA - excl[t]; }
  if (dupHi && rB >= excl[t] && rB - excl[t] < h[t]){ res[2] = (unsigned)t; res[3] = rB - excl[t]; }
  __syncthreads();
  if (!dupHi){
    h[t] = midB[t];
    __syncthreads();
    if (t == 0){ unsigned run = 0; for (int i = 0; i < 256; i++){ excl[i] = run; run += h[i]; } }
    __syncthreads();
    if (rB >= excl[t] && rB - excl[t] < h[t]){ res[2] = (unsigned)t; res[3] = rB - excl[t]; }
    __syncthreads();
  }
  unsigned mA = res[0], rA2 = res[1], mB = res[2], rB2 = res[3];
  bool dupMid = dupHi && (mA == mB);

  h[t] = h2A[mA*256 + t];
  __syncthreads();
  if (t == 0){ unsigned run = 0; for (int i = 0; i < 256; i++){ excl[i] = run; run += h[i]; } }
  __syncthreads();
  if (rA2 >= excl[t] && rA2 - excl[t] < h[t]) res[4] = (unsigned)t;
  if (dupMid && rB2 >= excl[t] && rB2 - excl[t] < h[t]) res[5] = (unsigned)t;
  __syncthreads();
  if (!dupMid){
    const unsigned* srcH = dupHi ? h2A : h2B;
    h[t] = srcH[mB*256 + t];
    __syncthreads();
    if (t == 0){ unsigned run = 0; for (int i = 0; i < 256; i++){ excl[i] = run; run += h[i]; } }
    __syncthreads();
    if (rB2 >= excl[t] && rB2 - excl[t] < h[t]) res[5] = (unsigned)t;
    __syncthreads();
  }
  if (t == 0){
    unsigned ka = (ha << 16) | (mA << 8) | res[4];
    unsigned kb = (hb << 16) | (mB << 8) | res[5];
    double va = (double)keyinv(ka), vb = (double)keyinv(kb);
    const double FRAC = 0.4*(double)(NN-1) - (double)RANK0;   // np's gamma
    sc->thr = va + (vb - va) * FRAC;
  }
}

// load cols q-1..q+4 of `row` with zero padding (rows and cols)
__device__ __forceinline__ void load6(const float* __restrict__ p, int row, int q, float r[6]){
  if (row < 0 || row >= HH){
    r[0]=r[1]=r[2]=r[3]=r[4]=r[5]=0.f;
    return;
  }
  const float* rp = p + (size_t)row * WW;
  float4 cc = *reinterpret_cast<const float4*>(rp + q);
  r[0] = (q > 0) ? rp[q-1] : 0.f;
  r[1]=cc.x; r[2]=cc.y; r[3]=cc.z; r[4]=cc.w;
  r[5] = (q+4 < WW) ? rp[q+4] : 0.f;
}

// balloon step: aux = 1 + M9(x) computed inline; xb = (origin > thr) ? aux : x.
// f64 partial sums of origin, xb, origin*xb per block. (round-3 verbatim)
__global__ __launch_bounds__(256)
void balloon_k(const float* __restrict__ x, const float* __restrict__ orig,
               float* __restrict__ xb, const Scal* __restrict__ sc, double* __restrict__ part){
  double thr = sc->thr;
  double s0 = 0.0, s1 = 0.0, s2 = 0.0;   // So, Sx, Sox
  const int nItems = NN/4;
  for (int it = blockIdx.x*blockDim.x + threadIdx.x; it < nItems; it += gridDim.x*blockDim.x){
    int i = it >> 9;
    int q = (it & 511) << 2;
    float a[6], b[6], c[6];
    load6(x, i-1, q, a);
    load6(x, i,   q, b);
    load6(x, i+1, q, c);
    float4 og = *reinterpret_cast<const float4*>(orig + (size_t)i*WW + q);
    float ov[4] = {og.x, og.y, og.z, og.w};
    float r[4];
    #pragma unroll
    for (int t = 0; t < 4; t++){
      float M9 = mx3(mx3(a[t],a[t+1],a[t+2]), mx3(b[t],b[t+1],b[t+2]), mx3(c[t],c[t+1],c[t+2]));
      float aux = 1.0f + M9;
      float nx = ((double)ov[t] > thr) ? aux : b[t+1];
      r[t] = nx;
      s0 += (double)ov[t];
      s1 += (double)nx;
      s2 += (double)ov[t] * (double)nx;
    }
    *reinterpret_cast<float4*>(xb + (size_t)i*WW + q) = make_float4(r[0],r[1],r[2],r[3]);
  }
  for (int off = 32; off > 0; off >>= 1){
    s0 += __shfl_down(s0, off);
    s1 += __shfl_down(s1, off);
    s2 += __shfl_down(s2, off);
  }
  __shared__ double red[4][3];
  int lane = threadIdx.x & 63, wv = threadIdx.x >> 6;
  if (lane == 0){ red[wv][0] = s0; red[wv][1] = s1; red[wv][2] = s2; }
  __syncthreads();
  if (threadIdx.x == 0){
    part[blockIdx.x*3+0] = red[0][0]+red[1][0]+red[2][0]+red[3][0];
    part[blockIdx.x*3+1] = red[0][1]+red[1][1]+red[2][1]+red[3][1];
    part[blockIdx.x*3+2] = red[0][2]+red[1][2]+red[2][2]+red[3][2];
  }
}

__global__ void c0c1_k(const double* __restrict__ part, Scal* __restrict__ sc){
  int t = threadIdx.x;
  double s0 = 0, s1 = 0, s2 = 0;
  for (int b = t; b < NPART; b += 256){
    s0 += part[b*3+0]; s1 += part[b*3+1]; s2 += part[b*3+2];
  }
  for (int off = 32; off > 0; off >>= 1){
    s0 += __shfl_down(s0, off);
    s1 += __shfl_down(s1, off);
    s2 += __shfl_down(s2, off);
  }
  __shared__ double red[4][3];
  int lane = t & 63, wv = t >> 6;
  if (lane == 0){ red[wv][0] = s0; red[wv][1] = s1; red[wv][2] = s2; }
  __syncthreads();
  if (t == 0){
    double So = red[0][0]+red[1][0]+red[2][0]+red[3][0];
    double Sx = red[0][1]+red[1][1]+red[2][1]+red[3][1];
    double Sox= red[0][2]+red[1][2]+red[2][2]+red[3][2];
    sc->c0 = (So - Sox) / ((double)NN - Sx + 1e-8);
    sc->c1 = Sox / (Sx + 1e-8);
  }
}

// final: elementwise Chan-Vese from origin + stored xb (round-3 verbatim)
__global__ __launch_bounds__(256)
void final_k(const float* __restrict__ orig, const float* __restrict__ xb,
             const Scal* __restrict__ sc, float* __restrict__ out){
  double c0 = sc->c0, c1 = sc->c1;
  const int nItems = NN/4;
  for (int it = blockIdx.x*blockDim.x + threadIdx.x; it < nItems; it += gridDim.x*blockDim.x){
    float4 og = reinterpret_cast<const float4*>(orig)[it];
    float4 xv = reinterpret_cast<const float4*>(xb)[it];
    float ov[4] = {og.x, og.y, og.z, og.w};
    float xx[4] = {xv.x, xv.y, xv.z, xv.w};
    float r[4];
    #pragma unroll
    for (int t = 0; t < 4; t++){
      double o = (double)ov[t];
      double d1 = o - c1, d0 = o - c0;
      double cv = d1*d1 - d0*d0;
      r[t] = (cv < 0.0) ? 1.0f : ((cv > 0.0) ? 0.0f : xx[t]);
    }
    reinterpret_cast<float4*>(out)[it] = make_float4(r[0],r[1],r[2],r[3]);
  }
}

extern "C" void kernel_launch(void* const* d_in, const int* in_sizes, int n_in,
                              void* d_out, int out_size, void* d_ws, size_t ws_size,
                              hipStream_t stream) {
  const float* input  = (const float*)d_in[0];
  const float* origin = (const float*)d_in[1];
  float* out = (float*)d_out;

  char* ws = (char*)d_ws;
  float*    bufA   = (float*)ws;
  unsigned* coarse = (unsigned*)(ws + OFF_COARSE);
  unsigned* under  = (unsigned*)(ws + OFF_UNDER);
  unsigned* over   = (unsigned*)(ws + OFF_OVER);
  unsigned* midA   = (unsigned*)(ws + OFF_MIDA);
  unsigned* midB   = (unsigned*)(ws + OFF_MIDB);
  unsigned* h2A    = (unsigned*)(ws + OFF_H2A);
  unsigned* h2B    = (unsigned*)(ws + OFF_H2B);
  Scal*     scal   = (Scal*)(ws + OFF_SCAL);
  double*   part   = (double*)(ws + OFF_PART);

  hipMemsetAsync(ws + OFF_CTL, 0, CTL_BYTES, stream);

  // all 6 smoothing ops + coarse hist in one tiled kernel (R3); x_final -> d_out
  fused_morph_k<<<(HH/TH)*(WW/TW), 256, 0, stream>>>(input, out, coarse, under, over);

  scan_coarse_k<<<1, 256, 0, stream>>>(coarse, under, scal);
  fine2d_k<<<1024, 256, 0, stream>>>(out, scal, midA, midB, h2A, h2B);
  scan_ml_k<<<1, 256, 0, stream>>>(midA, midB, h2A, h2B, scal);

  balloon_k<<<NPART, 256, 0, stream>>>(out, origin, bufA, scal, part);   // xb in bufA
  c0c1_k<<<1, 256, 0, stream>>>(part, scal);
  final_k<<<2048, 256, 0, stream>>>(origin, bufA, scal, out);
}

// Round 11
// 118.586 us; speedup vs baseline: 2.5916x; 1.0746x over previous
//
#include <hip/hip_runtime.h>

#define HH 2048
#define WW 2048
#define NN (HH*WW)

static constexpr unsigned RANK0 = 1677721u;   // floor(0.4*(NN-1))
static constexpr unsigned KEYLO = 0xB000u;
static constexpr unsigned KEYHI_ = 0xC000u;
static constexpr int NBINS = 4096;
static constexpr int NPART = 512;

// fused morph tile geometry: 32x128 tile, halo 6
#define TH 32
#define TW 128
#define LR 44            // TH + 12 rows (halo 6 each side)
#define LCP 148          // padded LDS row stride in floats (data cols [0,144))

struct Scal {
  unsigned keyhiA, keyhiB, rA, rB;
  double thr, c0, c1;
};

// ws layout: [bufA NN floats][zeroed ctl: coarse|under|over|midA|midB|h2A|h2B][scal][part]
static constexpr size_t OFF_CTL    = (size_t)NN * 4;
static constexpr size_t OFF_COARSE = OFF_CTL;
static constexpr size_t OFF_UNDER  = OFF_COARSE + (size_t)NBINS * 4;
static constexpr size_t OFF_OVER   = OFF_UNDER + 4;
static constexpr size_t OFF_MIDA   = OFF_OVER + 4;
static constexpr size_t OFF_MIDB   = OFF_MIDA + 1024;
static constexpr size_t OFF_H2A    = OFF_MIDB + 1024;
static constexpr size_t OFF_H2B    = OFF_H2A + 65536ull * 4;
static constexpr size_t CTL_END    = OFF_H2B + 65536ull * 4;
static constexpr size_t CTL_BYTES  = CTL_END - OFF_CTL;
static constexpr size_t OFF_SCAL   = CTL_END;                // 8-aligned
static constexpr size_t OFF_PART   = OFF_SCAL + 64;

__device__ __forceinline__ float mx3(float a, float b, float c){ return fmaxf(fmaxf(a,b),c); }
__device__ __forceinline__ float mn3(float a, float b, float c){ return fminf(fminf(a,b),c); }

__device__ __forceinline__ unsigned keyf(float x){
  unsigned b = __float_as_uint(x);
  return (b & 0x80000000u) ? ~b : (b | 0x80000000u);
}
__device__ __forceinline__ float keyinv(unsigned k){
  unsigned b = (k & 0x80000000u) ? (k ^ 0x80000000u) : ~k;
  return __uint_as_float(b);
}

// 6-float window from one LDS row: aligned b128 + two independent clamped b32
// reads (no shuffles, no branches). Clamp garbage only touches cols 0/143 which
// stay outside the pristine ring at every stage.
__device__ __forceinline__ void loadwin6(const float* __restrict__ src, int rowbase,
                                         int cL, int cC, int cR, float w[6]){
  float4 v = *reinterpret_cast<const float4*>(&src[rowbase + cC]);
  w[0] = src[rowbase + cL];
  w[1]=v.x; w[2]=v.y; w[3]=v.z; w[4]=v.w;
  w[5] = src[rowbase + cR];
}

__device__ __forceinline__ void morph4(bool DIL,
    const float pr[6], const float cr[6], const float nr[6], float w[4]){
  #pragma unroll
  for (int i = 0; i < 4; i++){
    if (DIL){
      float Ah = mx3(cr[i],   cr[i+1], cr[i+2]);
      float Av = mx3(pr[i+1], cr[i+1], nr[i+1]);
      float Ad = mx3(pr[i],   cr[i+1], nr[i+2]);
      float Aa = mx3(pr[i+2], cr[i+1], nr[i]);
      float tm = mx3(pr[i], pr[i+1], pr[i+2]);
      float bm = mx3(nr[i], nr[i+1], nr[i+2]);
      float M9 = mx3(tm, Ah, bm);
      w[i] = fmaxf(M9, 1.0f + fminf(fminf(Ah,Av), fminf(Ad,Aa)));
    } else {
      float Bh = mn3(cr[i],   cr[i+1], cr[i+2]);
      float Bv = mn3(pr[i+1], cr[i+1], nr[i+1]);
      float Bd = mn3(pr[i],   cr[i+1], nr[i+2]);
      float Ba = mn3(pr[i+2], cr[i+1], nr[i]);
      float tm = mn3(pr[i], pr[i+1], pr[i+2]);
      float bm = mn3(nr[i], nr[i+1], nr[i+2]);
      float m9 = mn3(tm, Bh, bm);
      w[i] = fminf(m9, fmaxf(fmaxf(Bh,Bv), fmaxf(Bd,Ba)) - 1.0f);
    }
  }
}

// All 6 smoothing ops (D,E,E,D,D,E) on a 32x128 tile, fully in LDS.
// ILP restructure of R3's stage loop: ALL 24 LDS reads of a stage (8 rows x
// {b128 + 2 edge b32}) are issued up front as independent ops, then 6 outputs
// computed from registers and written. No shuffles, no rolling-window chains.
__global__ __launch_bounds__(256)
void fused_morph_k(const float* __restrict__ in, float* __restrict__ out,
                   unsigned* __restrict__ gh, unsigned* __restrict__ under,
                   unsigned* __restrict__ over){
  __shared__ float lds[2][LR*LCP];
  const int tilec = blockIdx.x & 15;       // 16 col tiles
  const int tiler = blockIdx.x >> 4;       // 64 row tiles
  const int r0 = tiler*TH, c0 = tilec*TW;

  // ---- load 44 rows x 36 aligned float4 (cols c0-8 .. c0+136), zero-padded ----
  for (int idx = threadIdx.x; idx < LR*36; idx += 256){
    int lr = idx / 36, g = idx % 36;
    int gr = r0 - 6 + lr, gc = c0 - 8 + 4*g;
    float4 v = make_float4(0.f,0.f,0.f,0.f);
    if ((unsigned)gr < (unsigned)HH && (unsigned)gc < (unsigned)WW)
      v = *reinterpret_cast<const float4*>(in + (size_t)gr*WW + gc);
    *reinterpret_cast<float4*>(&lds[0][lr*LCP + 4*g]) = v;
  }
  __syncthreads();

  const int t = threadIdx.x;
  const int g = t % 36, s = t / 36;        // strip s covers compute rows [6s+1, 6s+7)
  const bool active = (t < 252);
  const int colC = 4*g;
  const int colL = g ? 4*g - 1 : 0;
  const int colR = (g == 35) ? 143 : 4*g + 4;
  const int gcBase = c0 - 8 + 4*g;
  const bool dilf[6] = {true,false,false,true,true,false};

  #pragma unroll 1
  for (int st = 0; st < 6; st++){
    const float* src = lds[st & 1];
    float*       dst = lds[(st & 1) ^ 1];
    if (active){
      const bool DIL = dilf[st];
      float r8[8][6];
      #pragma unroll
      for (int k = 0; k < 8; k++)
        loadwin6(src, (6*s + k)*LCP, colL, colC, colR, r8[k]);
      #pragma unroll
      for (int k = 0; k < 6; k++){
        float w[4];
        morph4(DIL, r8[k], r8[k+1], r8[k+2], w);
        int gr = r0 - 6 + 6*s + 1 + k;
        if ((unsigned)gr >= (unsigned)HH){
          w[0]=w[1]=w[2]=w[3]=0.f;
        } else {
          #pragma unroll
          for (int i = 0; i < 4; i++)
            if ((unsigned)(gcBase + i) >= (unsigned)WW) w[i] = 0.f;
        }
        *reinterpret_cast<float4*>(&dst[(6*s + 1 + k)*LCP + colC]) =
            make_float4(w[0],w[1],w[2],w[3]);
      }
    }
    __syncthreads();
  }
  // final values live in lds[0]; lds[1] is free -> coarse histogram storage
  unsigned* lh = reinterpret_cast<unsigned*>(&lds[1][0]);
  for (int i = threadIdx.x; i < NBINS; i += 256) lh[i] = 0;
  __syncthreads();

  unsigned uc = 0, oc = 0;
  for (int idx = threadIdx.x; idx < TH*(TW/4); idx += 256){
    int row = idx >> 5, gg = idx & 31;
    float4 v = *reinterpret_cast<const float4*>(&lds[0][(row+6)*LCP + 8 + 4*gg]);
    *reinterpret_cast<float4*>(out + (size_t)(r0+row)*WW + c0 + 4*gg) = v;
    float vv[4] = {v.x, v.y, v.z, v.w};
    #pragma unroll
    for (int i = 0; i < 4; i++){
      unsigned key = keyf(vv[i]);
      unsigned hi = key >> 16;
      if (hi >= KEYLO && hi < KEYHI_) atomicAdd(&lh[hi - KEYLO], 1u);
      else if (hi < KEYLO)            uc++;
      else                            oc++;
    }
  }
  __syncthreads();
  for (int i = threadIdx.x; i < NBINS; i += 256){
    unsigned c = lh[i];
    if (c) atomicAdd(&gh[i], c);
  }
  if (uc) atomicAdd(under, uc);
  if (oc) atomicAdd(over, oc);
}

__global__ void scan_coarse_k(const unsigned* __restrict__ gh, const unsigned* __restrict__ under,
                              Scal* __restrict__ sc){
  __shared__ unsigned part[256];
  __shared__ unsigned excl[256];
  int t = threadIdx.x;
  unsigned loc = 0;
  #pragma unroll
  for (int i = 0; i < NBINS/256; i++) loc += gh[t*(NBINS/256) + i];
  part[t] = loc;
  __syncthreads();
  if (t == 0){
    unsigned run = under[0];
    for (int i = 0; i < 256; i++){ excl[i] = run; run += part[i]; }
  }
  __syncthreads();
  unsigned run = excl[t];
  const unsigned r0 = RANK0, r1 = RANK0 + 1;
  #pragma unroll
  for (int i = 0; i < NBINS/256; i++){
    unsigned idx = t*(NBINS/256) + i;
    unsigned cc = gh[idx];
    if (cc){
      if (r0 >= run && r0 - run < cc){ sc->keyhiA = KEYLO + idx; sc->rA = r0 - run; }
      if (r1 >= run && r1 - run < cc){ sc->keyhiB = KEYLO + idx; sc->rB = r1 - run; }
    }
    run += cc;
  }
}

// ONE fine pass: 256-bin mid hist (LDS) + speculative 65536-bin (mid,low) 2D hist
__global__ __launch_bounds__(256)
void fine2d_k(const float* __restrict__ x, const Scal* __restrict__ sc,
              unsigned* __restrict__ midA, unsigned* __restrict__ midB,
              unsigned* __restrict__ h2A, unsigned* __restrict__ h2B){
  __shared__ unsigned hA[256], hB[256];
  hA[threadIdx.x] = 0; hB[threadIdx.x] = 0;
  __syncthreads();
  unsigned ha = sc->keyhiA, hb = sc->keyhiB;
  bool dup = (ha == hb);
  const int nItems = NN/4;
  for (int it = blockIdx.x*blockDim.x + threadIdx.x; it < nItems; it += gridDim.x*blockDim.x){
    float4 v = reinterpret_cast<const float4*>(x)[it];
    float vv[4] = {v.x, v.y, v.z, v.w};
    #pragma unroll
    for (int j = 0; j < 4; j++){
      unsigned key = keyf(vv[j]);
      unsigned hi = key >> 16;
      if (hi == ha){ atomicAdd(&hA[(key>>8)&255], 1u); atomicAdd(&h2A[key & 0xFFFFu], 1u); }
      else if (hi == hb){ atomicAdd(&hB[(key>>8)&255], 1u); atomicAdd(&h2B[key & 0xFFFFu], 1u); }
    }
  }
  __syncthreads();
  if (hA[threadIdx.x]) atomicAdd(&midA[threadIdx.x], hA[threadIdx.x]);
  if (!dup && hB[threadIdx.x]) atomicAdd(&midB[threadIdx.x], hB[threadIdx.x]);
}

// resolve mid byte (from midA/midB) then low byte (from the matching h2 row) -> thr
__global__ void scan_ml_k(const unsigned* __restrict__ midA, const unsigned* __restrict__ midB,
                          const unsigned* __restrict__ h2A, const unsigned* __restrict__ h2B,
                          Scal* __restrict__ sc){
  __shared__ unsigned h[256], excl[256];
  __shared__ unsigned res[6];   // mA, rA2, mB, rB2, lowA, lowB
  int t = threadIdx.x;
  unsigned ha = sc->keyhiA, hb = sc->keyhiB;
  bool dupHi = (ha == hb);
  unsigned rA = sc->rA, rB = sc->rB;

  h[t] = midA[t];
  __syncthreads();
  if (t == 0){ unsigned run = 0; for (int i = 0; i < 256; i++){ excl[i] = run; run += h[i]; } }
  __syncthreads();
  if (rA >= excl[t] && rA - excl[t] < h[t]){ res[0] = (unsigned)t; res[1] = rA - excl[t]; }
  if (dupHi && rB >= excl[t] && rB - excl[t] < h[t]){ res[2] = (unsigned)t; res[3] = rB - excl[t]; }
  __syncthreads();
  if (!dupHi){
    h[t] = midB[t];
    __syncthreads();
    if (t == 0){ unsigned run = 0; for (int i = 0; i < 256; i++){ excl[i] = run; run += h[i]; } }
    __syncthreads();
    if (rB >= excl[t] && rB - excl[t] < h[t]){ res[2] = (unsigned)t; res[3] = rB - excl[t]; }
    __syncthreads();
  }
  unsigned mA = res[0], rA2 = res[1], mB = res[2], rB2 = res[3];
  bool dupMid = dupHi && (mA == mB);

  h[t] = h2A[mA*256 + t];
  __syncthreads();
  if (t == 0){ unsigned run = 0; for (int i = 0; i < 256; i++){ excl[i] = run; run += h[i]; } }
  __syncthreads();
  if (rA2 >= excl[t] && rA2 - excl[t] < h[t]) res[4] = (unsigned)t;
  if (dupMid && rB2 >= excl[t] && rB2 - excl[t] < h[t]) res[5] = (unsigned)t;
  __syncthreads();
  if (!dupMid){
    const unsigned* srcH = dupHi ? h2A : h2B;
    h[t] = srcH[mB*256 + t];
    __syncthreads();
    if (t == 0){ unsigned run = 0; for (int i = 0; i < 256; i++){ excl[i] = run; run += h[i]; } }
    __syncthreads();
    if (rB2 >= excl[t] && rB2 - excl[t] < h[t]) res[5] = (unsigned)t;
    __syncthreads();
  }
  if (t == 0){
    unsigned ka = (ha << 16) | (mA << 8) | res[4];
    unsigned kb = (hb << 16) | (mB << 8) | res[5];
    double va = (double)keyinv(ka), vb = (double)keyinv(kb);
    const double FRAC = 0.4*(double)(NN-1) - (double)RANK0;   // np's gamma
    sc->thr = va + (vb - va) * FRAC;
  }
}

// load cols q-1..q+4 of `row` with zero padding (rows and cols)
__device__ __forceinline__ void load6(const float* __restrict__ p, int row, int q, float r[6]){
  if (row < 0 || row >= HH){
    r[0]=r[1]=r[2]=r[3]=r[4]=r[5]=0.f;
    return;
  }
  const float* rp = p + (size_t)row * WW;
  float4 cc = *reinterpret_cast<const float4*>(rp + q);
  r[0] = (q > 0) ? rp[q-1] : 0.f;
  r[1]=cc.x; r[2]=cc.y; r[3]=cc.z; r[4]=cc.w;
  r[5] = (q+4 < WW) ? rp[q+4] : 0.f;
}

// balloon step: aux = 1 + M9(x) computed inline; xb = (origin > thr) ? aux : x.
// f64 partial sums of origin, xb, origin*xb per block.
__global__ __launch_bounds__(256)
void balloon_k(const float* __restrict__ x, const float* __restrict__ orig,
               float* __restrict__ xb, const Scal* __restrict__ sc, double* __restrict__ part){
  double thr = sc->thr;
  double s0 = 0.0, s1 = 0.0, s2 = 0.0;   // So, Sx, Sox
  const int nItems = NN/4;
  for (int it = blockIdx.x*blockDim.x + threadIdx.x; it < nItems; it += gridDim.x*blockDim.x){
    int i = it >> 9;
    int q = (it & 511) << 2;
    float a[6], b[6], c[6];
    load6(x, i-1, q, a);
    load6(x, i,   q, b);
    load6(x, i+1, q, c);
    float4 og = *reinterpret_cast<const float4*>(orig + (size_t)i*WW + q);
    float ov[4] = {og.x, og.y, og.z, og.w};
    float r[4];
    #pragma unroll
    for (int t = 0; t < 4; t++){
      float M9 = mx3(mx3(a[t],a[t+1],a[t+2]), mx3(b[t],b[t+1],b[t+2]), mx3(c[t],c[t+1],c[t+2]));
      float aux = 1.0f + M9;
      float nx = ((double)ov[t] > thr) ? aux : b[t+1];
      r[t] = nx;
      s0 += (double)ov[t];
      s1 += (double)nx;
      s2 += (double)ov[t] * (double)nx;
    }
    *reinterpret_cast<float4*>(xb + (size_t)i*WW + q) = make_float4(r[0],r[1],r[2],r[3]);
  }
  for (int off = 32; off > 0; off >>= 1){
    s0 += __shfl_down(s0, off);
    s1 += __shfl_down(s1, off);
    s2 += __shfl_down(s2, off);
  }
  __shared__ double red[4][3];
  int lane = threadIdx.x & 63, wv = threadIdx.x >> 6;
  if (lane == 0){ red[wv][0] = s0; red[wv][1] = s1; red[wv][2] = s2; }
  __syncthreads();
  if (threadIdx.x == 0){
    part[blockIdx.x*3+0] = red[0][0]+red[1][0]+red[2][0]+red[3][0];
    part[blockIdx.x*3+1] = red[0][1]+red[1][1]+red[2][1]+red[3][1];
    part[blockIdx.x*3+2] = red[0][2]+red[1][2]+red[2][2]+red[3][2];
  }
}

__global__ void c0c1_k(const double* __restrict__ part, Scal* __restrict__ sc){
  int t = threadIdx.x;
  double s0 = 0, s1 = 0, s2 = 0;
  for (int b = t; b < NPART; b += 256){
    s0 += part[b*3+0]; s1 += part[b*3+1]; s2 += part[b*3+2];
  }
  for (int off = 32; off > 0; off >>= 1){
    s0 += __shfl_down(s0, off);
    s1 += __shfl_down(s1, off);
    s2 += __shfl_down(s2, off);
  }
  __shared__ double red[4][3];
  int lane = t & 63, wv = t >> 6;
  if (lane == 0){ red[wv][0] = s0; red[wv][1] = s1; red[wv][2] = s2; }
  __syncthreads();
  if (t == 0){
    double So = red[0][0]+red[1][0]+red[2][0]+red[3][0];
    double Sx = red[0][1]+red[1][1]+red[2][1]+red[3][1];
    double Sox= red[0][2]+red[1][2]+red[2][2]+red[3][2];
    sc->c0 = (So - Sox) / ((double)NN - Sx + 1e-8);
    sc->c1 = Sox / (Sx + 1e-8);
  }
}

// final: elementwise Chan-Vese from origin + stored xb
__global__ __launch_bounds__(256)
void final_k(const float* __restrict__ orig, const float* __restrict__ xb,
             const Scal* __restrict__ sc, float* __restrict__ out){
  double c0 = sc->c0, c1 = sc->c1;
  const int nItems = NN/4;
  for (int it = blockIdx.x*blockDim.x + threadIdx.x; it < nItems; it += gridDim.x*blockDim.x){
    float4 og = reinterpret_cast<const float4*>(orig)[it];
    float4 xv = reinterpret_cast<const float4*>(xb)[it];
    float ov[4] = {og.x, og.y, og.z, og.w};
    float xx[4] = {xv.x, xv.y, xv.z, xv.w};
    float r[4];
    #pragma unroll
    for (int t = 0; t < 4; t++){
      double o = (double)ov[t];
      double d1 = o - c1, d0 = o - c0;
      double cv = d1*d1 - d0*d0;
      r[t] = (cv < 0.0) ? 1.0f : ((cv > 0.0) ? 0.0f : xx[t]);
    }
    reinterpret_cast<float4*>(out)[it] = make_float4(r[0],r[1],r[2],r[3]);
  }
}

extern "C" void kernel_launch(void* const* d_in, const int* in_sizes, int n_in,
                              void* d_out, int out_size, void* d_ws, size_t ws_size,
                              hipStream_t stream) {
  const float* input  = (const float*)d_in[0];
  const float* origin = (const float*)d_in[1];
  float* out = (float*)d_out;

  char* ws = (char*)d_ws;
  float*    bufA   = (float*)ws;
  unsigned* coarse = (unsigned*)(ws + OFF_COARSE);
  unsigned* under  = (unsigned*)(ws + OFF_UNDER);
  unsigned* over   = (unsigned*)(ws + OFF_OVER);
  unsigned* midA   = (unsigned*)(ws + OFF_MIDA);
  unsigned* midB   = (unsigned*)(ws + OFF_MIDB);
  unsigned* h2A    = (unsigned*)(ws + OFF_H2A);
  unsigned* h2B    = (unsigned*)(ws + OFF_H2B);
  Scal*     scal   = (Scal*)(ws + OFF_SCAL);
  double*   part   = (double*)(ws + OFF_PART);

  hipMemsetAsync(ws + OFF_CTL, 0, CTL_BYTES, stream);

  // all 6 smoothing ops + coarse hist in one tiled kernel; x_final -> d_out
  fused_morph_k<<<(HH/TH)*(WW/TW), 256, 0, stream>>>(input, out, coarse, under, over);

  scan_coarse_k<<<1, 256, 0, stream>>>(coarse, under, scal);
  fine2d_k<<<1024, 256, 0, stream>>>(out, scal, midA, midB, h2A, h2B);
  scan_ml_k<<<1, 256, 0, stream>>>(midA, midB, h2A, h2B, scal);

  balloon_k<<<NPART, 256, 0, stream>>>(out, origin, bufA, scal, part);   // xb in bufA
  c0c1_k<<<1, 256, 0, stream>>>(part, scal);
  final_k<<<2048, 256, 0, stream>>>(origin, bufA, scal, out);
}